// Round 3
// baseline (228.073 us; speedup 1.0000x reference)
//
#include <hip/hip_runtime.h>
#include <hip/hip_cooperative_groups.h>

namespace cg = cooperative_groups;

#define N_NODES 50000
#define N_EDGES 640000
#define D 128

typedef float  f4 __attribute__((ext_vector_type(4)));
typedef int    i4 __attribute__((ext_vector_type(4)));

// Fused single-launch kernel (cooperative).
// Phase 1: 16 lanes per node; lane sl loads X[n][sl*8..sl*8+7] as two float4
//          (32B/lane, 512B contiguous per node, nontemporal — X is streamed
//          once). Butterfly-reduce over the 16-lane group -> s1[n], s2[n].
// grid.sync()
// Phase 2: out[e] = s1[src[e]] + s2[dst[e]], 4 edges/thread, int4 index
//          loads, gathers hit the 400KB L2-resident tables, float4 NT stores.
__global__ __launch_bounds__(256) void fused_edge_decoder(
    const float* __restrict__ X,
    const int*   __restrict__ src,
    const int*   __restrict__ dst,
    const float* __restrict__ W1,
    const float* __restrict__ W2,
    float* __restrict__ s1,
    float* __restrict__ s2,
    float* __restrict__ out,
    int total_groups)
{
    const int lane = threadIdx.x & 63;
    const int sl   = lane & 15;          // lane within 16-lane group
    const int sub  = lane >> 4;          // group within wave (0..3)
    const int wave = blockIdx.x * (blockDim.x >> 6) + (threadIdx.x >> 6);
    const int g    = wave * 4 + sub;     // global 16-lane group id

    // W fragments in registers for the whole phase.
    const f4* W1v = (const f4*)W1;
    const f4* W2v = (const f4*)W2;
    const f4 w1a = W1v[sl * 2], w1b = W1v[sl * 2 + 1];
    const f4 w2a = W2v[sl * 2], w2b = W2v[sl * 2 + 1];

    for (int n = g; n < N_NODES; n += total_groups) {
        const f4* Xv = (const f4*)(X + (size_t)n * D);
        const f4 x0 = __builtin_nontemporal_load(&Xv[sl * 2]);
        const f4 x1 = __builtin_nontemporal_load(&Xv[sl * 2 + 1]);
        float p1 = x0.x * w1a.x + x0.y * w1a.y + x0.z * w1a.z + x0.w * w1a.w
                 + x1.x * w1b.x + x1.y * w1b.y + x1.z * w1b.z + x1.w * w1b.w;
        float p2 = x0.x * w2a.x + x0.y * w2a.y + x0.z * w2a.z + x0.w * w2a.w
                 + x1.x * w2b.x + x1.y * w2b.y + x1.z * w2b.z + x1.w * w2b.w;
        // Reduce across the 16-lane group (xor offsets < 16 stay in-group).
        #pragma unroll
        for (int off = 8; off > 0; off >>= 1) {
            p1 += __shfl_xor(p1, off, 64);
            p2 += __shfl_xor(p2, off, 64);
        }
        if (sl == 0) {
            s1[n] = p1;
            s2[n] = p2;
        }
    }

    // Device-scope visibility of s1/s2 across XCDs, then grid-wide barrier.
    __threadfence();
    cg::this_grid().sync();

    const int nthreads = gridDim.x * blockDim.x;
    const int tid = blockIdx.x * blockDim.x + threadIdx.x;
    for (int i = tid; i < N_EDGES / 4; i += nthreads) {
        const i4 s = __builtin_nontemporal_load(&((const i4*)src)[i]);
        const i4 d = __builtin_nontemporal_load(&((const i4*)dst)[i]);
        f4 o;
        o.x = s1[s.x] + s2[d.x];
        o.y = s1[s.y] + s2[d.y];
        o.z = s1[s.z] + s2[d.z];
        o.w = s1[s.w] + s2[d.w];
        __builtin_nontemporal_store(o, &((f4*)out)[i]);
    }
}

extern "C" void kernel_launch(void* const* d_in, const int* in_sizes, int n_in,
                              void* d_out, int out_size, void* d_ws, size_t ws_size,
                              hipStream_t stream) {
    const float* X  = (const float*)d_in[0];   // [N_NODES, D]
    const int*   ei = (const int*)d_in[1];     // [2, N_EDGES] (int32 on device)
    const float* W1 = (const float*)d_in[2];   // [1, D]
    const float* W2 = (const float*)d_in[3];   // [1, D]
    float* out = (float*)d_out;                // [N_EDGES, 1]

    // Workspace: two per-node scalar tables (fully overwritten each call).
    float* s1 = (float*)d_ws;
    float* s2 = s1 + N_NODES;

    const int blocks = 1024;                   // 4 blocks/CU — co-resident
    const int total_groups = blocks * 16;      // 16384 16-lane groups
    const int* src = ei;
    const int* dst = ei + N_EDGES;

    void* args[] = {(void*)&X, (void*)&src, (void*)&dst, (void*)&W1,
                    (void*)&W2, (void*)&s1, (void*)&s2, (void*)&out,
                    (void*)&total_groups};
    hipLaunchCooperativeKernel((const void*)fused_edge_decoder,
                               dim3(blocks), dim3(256), args, 0, stream);
}

// Round 4
// 84.087 us; speedup vs baseline: 2.7123x; 2.7123x over previous
//
#include <hip/hip_runtime.h>

#define N_NODES 50000
#define N_EDGES 640000
#define D 128

typedef float  f4 __attribute__((ext_vector_type(4)));
typedef float  f2 __attribute__((ext_vector_type(2)));
typedef int    i2 __attribute__((ext_vector_type(2)));

// Kernel 1: two adjacent nodes per 16-lane group (ILP=2).
// Group g handles nodes 2g and 2g+1: lane sl loads X[2g][sl*8..+7] and
// X[2g+1][sl*8..+7] as four float4 (64B/lane in flight; each wave covers
// 4KB contiguous). Four independent butterfly-reduce chains (4 steps).
// Lane 0 stores s1[2g..2g+1] / s2[2g..2g+1] as float2.
__global__ __launch_bounds__(256) void node_scores_kernel(
    const float* __restrict__ X,
    const float* __restrict__ W1,
    const float* __restrict__ W2,
    float* __restrict__ s1,
    float* __restrict__ s2)
{
    const int lane = threadIdx.x & 63;
    const int sl   = lane & 15;          // lane within 16-lane group
    const int sub  = lane >> 4;          // group within wave (0..3)
    const int wave = blockIdx.x * (blockDim.x >> 6) + (threadIdx.x >> 6);
    const int g    = wave * 4 + sub;     // group id: handles nodes 2g, 2g+1
    if (g >= N_NODES / 2) return;

    const f4* W1v = (const f4*)W1;
    const f4* W2v = (const f4*)W2;
    const f4 w1a = W1v[sl * 2], w1b = W1v[sl * 2 + 1];
    const f4 w2a = W2v[sl * 2], w2b = W2v[sl * 2 + 1];

    // Node pair base: X + 2g*128 floats; node 2g+1 is +32 f4 further.
    const f4* Xv = (const f4*)(X + (size_t)(2 * g) * D);
    const f4 xa0 = Xv[sl * 2];
    const f4 xa1 = Xv[sl * 2 + 1];
    const f4 xb0 = Xv[32 + sl * 2];
    const f4 xb1 = Xv[32 + sl * 2 + 1];

    float p1a = xa0.x * w1a.x + xa0.y * w1a.y + xa0.z * w1a.z + xa0.w * w1a.w
              + xa1.x * w1b.x + xa1.y * w1b.y + xa1.z * w1b.z + xa1.w * w1b.w;
    float p2a = xa0.x * w2a.x + xa0.y * w2a.y + xa0.z * w2a.z + xa0.w * w2a.w
              + xa1.x * w2b.x + xa1.y * w2b.y + xa1.z * w2b.z + xa1.w * w2b.w;
    float p1b = xb0.x * w1a.x + xb0.y * w1a.y + xb0.z * w1a.z + xb0.w * w1a.w
              + xb1.x * w1b.x + xb1.y * w1b.y + xb1.z * w1b.z + xb1.w * w1b.w;
    float p2b = xb0.x * w2a.x + xb0.y * w2a.y + xb0.z * w2a.z + xb0.w * w2a.w
              + xb1.x * w2b.x + xb1.y * w2b.y + xb1.z * w2b.z + xb1.w * w2b.w;

    // Four independent reductions across the 16-lane group.
    #pragma unroll
    for (int off = 8; off > 0; off >>= 1) {
        p1a += __shfl_xor(p1a, off, 64);
        p2a += __shfl_xor(p2a, off, 64);
        p1b += __shfl_xor(p1b, off, 64);
        p2b += __shfl_xor(p2b, off, 64);
    }
    if (sl == 0) {
        f2 v1; v1.x = p1a; v1.y = p1b;
        f2 v2; v2.x = p2a; v2.y = p2b;
        ((f2*)s1)[g] = v1;
        ((f2*)s2)[g] = v2;
    }
}

// Kernel 2: out[e] = s1[src[e]] + s2[dst[e]]; 2 edges per thread.
// 320000 threads -> 1250 blocks of 256 (~20 waves/CU for gather-latency
// hiding, short per-thread dependency chains). int2 index loads, gathers
// hit the 400KB L2-resident tables, float2 nontemporal stores.
__global__ __launch_bounds__(256) void edge_combine_kernel(
    const int* __restrict__ src,
    const int* __restrict__ dst,
    const float* __restrict__ s1,
    const float* __restrict__ s2,
    float* __restrict__ out)
{
    const int i = blockIdx.x * blockDim.x + threadIdx.x;   // exact: 320000
    const i2 s = ((const i2*)src)[i];
    const i2 d = ((const i2*)dst)[i];
    f2 o;
    o.x = s1[s.x] + s2[d.x];
    o.y = s1[s.y] + s2[d.y];
    __builtin_nontemporal_store(o, &((f2*)out)[i]);
}

extern "C" void kernel_launch(void* const* d_in, const int* in_sizes, int n_in,
                              void* d_out, int out_size, void* d_ws, size_t ws_size,
                              hipStream_t stream) {
    const float* X  = (const float*)d_in[0];   // [N_NODES, D]
    const int*   ei = (const int*)d_in[1];     // [2, N_EDGES] (int32 on device)
    const float* W1 = (const float*)d_in[2];   // [1, D]
    const float* W2 = (const float*)d_in[3];   // [1, D]
    float* out = (float*)d_out;                // [N_EDGES, 1]

    // Workspace: two per-node scalar tables (fully overwritten each call).
    float* s1 = (float*)d_ws;
    float* s2 = s1 + N_NODES;

    // Kernel 1: 25000 node-pair groups -> 1563 blocks x 16 groups.
    const int groups1 = N_NODES / 2;                    // 25000
    const int blocks1 = (groups1 + 15) / 16;            // 1563
    node_scores_kernel<<<blocks1, 256, 0, stream>>>(X, W1, W2, s1, s2);

    // Kernel 2: 320000 threads (2 edges each) -> 1250 blocks of 256, exact.
    const int n2 = N_EDGES / 2;                         // 320000
    edge_combine_kernel<<<n2 / 256, 256, 0, stream>>>(
        ei, ei + N_EDGES, s1, s2, out);
}